// Round 1
// baseline (16764.906 us; speedup 1.0000x reference)
//
#include <hip/hip_runtime.h>
#include <cstdint>
#include <cstddef>

// Problem constants (fixed by setup_inputs)
constexpr int B_  = 16;
constexpr int T_  = 1024;
constexpr int C_  = 768;
constexpr int H_  = 12;
constexpr int HD_ = 64;
constexpr int BT_ = B_ * T_;      // 16384
constexpr int C3_ = 3 * C_;       // 2304
constexpr int FF_ = 4 * C_;       // 3072
constexpr int MCH_ = 8192;        // MoE row chunk

// ---------------------------------------------------------------------------
// LayerNorm: one block (256 threads) per row of 768
// ---------------------------------------------------------------------------
__launch_bounds__(256)
__global__ void ln_kernel(const float* __restrict__ x, const float* __restrict__ w,
                          const float* __restrict__ b, float* __restrict__ out) {
  int row = blockIdx.x;
  int tid = threadIdx.x;
  const float* xr = x + (size_t)row * C_;
  float v0 = xr[tid], v1 = xr[tid + 256], v2 = xr[tid + 512];
  float s  = v0 + v1 + v2;
  float ss = v0 * v0 + v1 * v1 + v2 * v2;
#pragma unroll
  for (int off = 32; off > 0; off >>= 1) {
    s  += __shfl_down(s, off, 64);
    ss += __shfl_down(ss, off, 64);
  }
  __shared__ float red[8];
  int wid = tid >> 6;
  if ((tid & 63) == 0) { red[wid] = s; red[4 + wid] = ss; }
  __syncthreads();
  float st  = red[0] + red[1] + red[2] + red[3];
  float sst = red[4] + red[5] + red[6] + red[7];
  float mean = st * (1.0f / C_);
  float var  = sst * (1.0f / C_) - mean * mean;
  float rstd = rsqrtf(var + 1e-5f);
  float* orow = out + (size_t)row * C_;
  orow[tid]       = (v0 - mean) * rstd * w[tid]       + b[tid];
  orow[tid + 256] = (v1 - mean) * rstd * w[tid + 256] + b[tid + 256];
  orow[tid + 512] = (v2 - mean) * rstd * w[tid + 512] + b[tid + 512];
}

// ---------------------------------------------------------------------------
// Generic f32 GEMM: C = act(A@B [+bias]) [+R]
// A[M,K], B[K,N], C[M,N] row-major. M%128==0, N%128==0, K%8==0.
// 128x128 tile per 256-thread block, 8x8 microtile per thread, K-tile 8.
// ACT: 0 = none, 1 = leaky-relu(0.01)
// ---------------------------------------------------------------------------
template <int ACT, bool BIAS, bool RES>
__launch_bounds__(256)
__global__ void gemm_f32(const float* __restrict__ A, const float* __restrict__ Bm,
                         const float* __restrict__ bias, const float* __restrict__ Rres,
                         float* __restrict__ C, int M, int N, int K) {
  __shared__ float As[8][129];   // transposed A tile: As[k][m]
  __shared__ float Bs[8][128];   // Bs[k][n]
  int tid = threadIdx.x;
  int tx = tid & 15;             // n dimension
  int ty = tid >> 4;             // m dimension
  int n0 = blockIdx.x * 128;
  int m0 = blockIdx.y * 128;
  int am = tid >> 1, ak = (tid & 1) << 2;       // A tile load: float4 over k
  int bk = tid >> 5, bn = (tid & 31) << 2;      // B tile load: float4 over n
  float acc[8][8];
#pragma unroll
  for (int i = 0; i < 8; ++i)
#pragma unroll
    for (int j = 0; j < 8; ++j) acc[i][j] = 0.0f;

  for (int k0 = 0; k0 < K; k0 += 8) {
    __syncthreads();
    float4 av = *(const float4*)&A[(size_t)(m0 + am) * K + k0 + ak];
    As[ak + 0][am] = av.x;
    As[ak + 1][am] = av.y;
    As[ak + 2][am] = av.z;
    As[ak + 3][am] = av.w;
    *(float4*)&Bs[bk][bn] = *(const float4*)&Bm[(size_t)(k0 + bk) * N + n0 + bn];
    __syncthreads();
#pragma unroll
    for (int k = 0; k < 8; ++k) {
      float a[8], bfr[8];
#pragma unroll
      for (int i = 0; i < 8; ++i) a[i] = As[k][ty + 16 * i];
#pragma unroll
      for (int j = 0; j < 8; ++j) bfr[j] = Bs[k][tx + 16 * j];
#pragma unroll
      for (int i = 0; i < 8; ++i)
#pragma unroll
        for (int j = 0; j < 8; ++j) acc[i][j] += a[i] * bfr[j];
    }
  }

#pragma unroll
  for (int i = 0; i < 8; ++i) {
    int row = m0 + ty + 16 * i;
#pragma unroll
    for (int j = 0; j < 8; ++j) {
      int col = n0 + tx + 16 * j;
      float v = acc[i][j];
      if (BIAS) v += bias[col];
      if (ACT == 1) v = (v >= 0.0f) ? v : 0.01f * v;
      if (RES) v += Rres[(size_t)row * N + col];
      C[(size_t)row * N + col] = v;
    }
  }
}

// ---------------------------------------------------------------------------
// Flash-style causal attention. qkv: [B*T, 3C] (q|k|v blocks, col = h*64+d).
// Output y: [B*T, C] (already in (B,T,H*hd) layout).
// Block: 256 threads = 32 q-rows x 8 lanes; K-tiles of 64.
// ---------------------------------------------------------------------------
__launch_bounds__(256)
__global__ void attn_kernel(const float* __restrict__ qkv, float* __restrict__ y) {
  __shared__ float Qs[32][68];   // [q][d], scaled by 1/8
  __shared__ float KsT[64][68];  // [d][k_local]  (transposed for float4 reads)
  __shared__ float Vs[64][68];   // [k_local][d]
  __shared__ float Ps[32][65];   // [q][k_local] softmax numerators
  int tid = threadIdx.x;
  int tx = tid & 7;    // 0..7
  int ty = tid >> 3;   // 0..31: q row within tile
  int q0 = blockIdx.x * 32;
  int bh = blockIdx.y;
  int b = bh / H_, h = bh % H_;
  const size_t base = (size_t)b * T_ * C3_ + (size_t)h * HD_;

  {  // load Q tile, pre-scaled by 1/sqrt(hd)
    const float* src = qkv + base + (size_t)(q0 + ty) * C3_ + tx * 8;
    float4 a = *(const float4*)src;
    float4 c = *(const float4*)(src + 4);
    const float sc = 0.125f;
    a.x *= sc; a.y *= sc; a.z *= sc; a.w *= sc;
    c.x *= sc; c.y *= sc; c.z *= sc; c.w *= sc;
    *(float4*)&Qs[ty][tx * 8]     = a;
    *(float4*)&Qs[ty][tx * 8 + 4] = c;
  }

  float O[8] = {0, 0, 0, 0, 0, 0, 0, 0};
  float mrow = -1e30f, lrow = 0.0f;
  int nkt = (q0 + 95) >> 6;       // k-tiles needed to cover k <= q0+31
  int lr = tid >> 2;              // 0..63: k row for loads
  int lc = (tid & 3) << 4;        // 0,16,32,48

  for (int kt = 0; kt < nkt; ++kt) {
    int k0 = kt << 6;
    __syncthreads();  // previous tile fully consumed
    {
      const float* kp = qkv + base + (size_t)(k0 + lr) * C3_ + C_ + lc;
      const float* vp = kp + C_;
#pragma unroll
      for (int j = 0; j < 16; j += 4) {
        float4 kv = *(const float4*)(kp + j);
        KsT[lc + j + 0][lr] = kv.x;
        KsT[lc + j + 1][lr] = kv.y;
        KsT[lc + j + 2][lr] = kv.z;
        KsT[lc + j + 3][lr] = kv.w;
        *(float4*)&Vs[lr][lc + j] = *(const float4*)(vp + j);
      }
    }
    __syncthreads();

    // scores for 8 k positions: kl = tx*8 + kk
    float s[8] = {0, 0, 0, 0, 0, 0, 0, 0};
#pragma unroll
    for (int d = 0; d < 64; ++d) {
      float qd = Qs[ty][d];
      float4 k0v = *(const float4*)&KsT[d][tx * 8];
      float4 k1v = *(const float4*)&KsT[d][tx * 8 + 4];
      s[0] += qd * k0v.x; s[1] += qd * k0v.y; s[2] += qd * k0v.z; s[3] += qd * k0v.w;
      s[4] += qd * k1v.x; s[5] += qd * k1v.y; s[6] += qd * k1v.z; s[7] += qd * k1v.w;
    }
    int qg = q0 + ty;
#pragma unroll
    for (int kk = 0; kk < 8; ++kk)
      if (k0 + tx * 8 + kk > qg) s[kk] = -1e30f;

    float tmax = s[0];
#pragma unroll
    for (int kk = 1; kk < 8; ++kk) tmax = fmaxf(tmax, s[kk]);
    tmax = fmaxf(tmax, __shfl_xor(tmax, 1, 64));
    tmax = fmaxf(tmax, __shfl_xor(tmax, 2, 64));
    tmax = fmaxf(tmax, __shfl_xor(tmax, 4, 64));
    float mnew  = fmaxf(mrow, tmax);
    float alpha = __expf(mrow - mnew);
    float psum = 0.0f;
#pragma unroll
    for (int kk = 0; kk < 8; ++kk) {
      float p = __expf(s[kk] - mnew);
      Ps[ty][tx * 8 + kk] = p;
      psum += p;
    }
    psum += __shfl_xor(psum, 1, 64);
    psum += __shfl_xor(psum, 2, 64);
    psum += __shfl_xor(psum, 4, 64);
    lrow = lrow * alpha + psum;
    mrow = mnew;
#pragma unroll
    for (int i = 0; i < 8; ++i) O[i] *= alpha;
    // O += P @ V   (Ps row is produced & consumed by the same wave)
#pragma unroll
    for (int kk = 0; kk < 64; ++kk) {
      float p = Ps[ty][kk];
      float4 v0 = *(const float4*)&Vs[kk][tx * 8];
      float4 v1 = *(const float4*)&Vs[kk][tx * 8 + 4];
      O[0] += p * v0.x; O[1] += p * v0.y; O[2] += p * v0.z; O[3] += p * v0.w;
      O[4] += p * v1.x; O[5] += p * v1.y; O[6] += p * v1.z; O[7] += p * v1.w;
    }
  }

  float inv = 1.0f / lrow;
  float* dst = y + ((size_t)b * T_ + q0 + ty) * C_ + h * HD_ + tx * 8;
  float4 o0 = make_float4(O[0] * inv, O[1] * inv, O[2] * inv, O[3] * inv);
  float4 o1 = make_float4(O[4] * inv, O[5] * inv, O[6] * inv, O[7] * inv);
  *(float4*)dst       = o0;
  *(float4*)(dst + 4) = o1;
}

// ---------------------------------------------------------------------------
// Gating: one wave per token. logits = h2[t] @ wg (768x2), p = softmax.
// Stores normalized gates; accumulates density counts (argmax) and proxy sums.
// ---------------------------------------------------------------------------
__launch_bounds__(256)
__global__ void gate_kernel(const float* __restrict__ h2, const float* __restrict__ wg,
                            float* __restrict__ gates, float* __restrict__ dens,
                            float* __restrict__ prox) {
  int wave = threadIdx.x >> 6, lane = threadIdx.x & 63;
  int t = blockIdx.x * 4 + wave;
  const float* hr = h2 + (size_t)t * C_;
  float a0 = 0.0f, a1 = 0.0f;
#pragma unroll
  for (int i = 0; i < 12; ++i) {
    int d = lane + 64 * i;
    float hv = hr[d];
    a0 += hv * wg[2 * d];
    a1 += hv * wg[2 * d + 1];
  }
#pragma unroll
  for (int off = 32; off > 0; off >>= 1) {
    a0 += __shfl_down(a0, off, 64);
    a1 += __shfl_down(a1, off, 64);
  }
  if (lane == 0) {
    float m  = fmaxf(a0, a1);
    float e0 = __expf(a0 - m), e1 = __expf(a1 - m);
    float invs = 1.0f / (e0 + e1);
    float p0 = e0 * invs, p1 = e1 * invs;
    const float gnorm = 1.0f / (1.0f + 1e-9f);
    gates[2 * t]     = p0 * gnorm;
    gates[2 * t + 1] = p1 * gnorm;
    int bidx = t >> 10;   // t / T
    int idx1 = (p1 > p0) ? 1 : 0;
    atomicAdd(&dens[bidx * 2 + idx1], 1.0f);
    atomicAdd(&prox[bidx * 2 + 0], p0);
    atomicAdd(&prox[bidx * 2 + 1], p1);
  }
}

// ---------------------------------------------------------------------------
// Combine: out[r0+rl, :] += gates[r, e] * eo[rl, :]  (float4 grid)
// grid*block == MCH_*C_/4 exactly
// ---------------------------------------------------------------------------
__launch_bounds__(256)
__global__ void combine_kernel(float* __restrict__ out, const float* __restrict__ eo,
                               const float* __restrict__ gates, int r0, int e) {
  int idx = blockIdx.x * 256 + threadIdx.x;    // float4 index within chunk
  int rl = idx / (C_ / 4);
  int r = r0 + rl;
  float g = gates[2 * r + e];
  float4 v = ((const float4*)eo)[idx];
  float4* op = (float4*)out + (size_t)r0 * (C_ / 4) + idx;
  float4 o = *op;
  o.x += g * v.x; o.y += g * v.y; o.z += g * v.z; o.w += g * v.w;
  *op = o;
}

// ---------------------------------------------------------------------------
// aux_loss = mean_{b,e}(density * proxy) * E^2 ; density=cnt/T, proxy=sum/T
// ---------------------------------------------------------------------------
__global__ void aux_kernel(const float* __restrict__ dens, const float* __restrict__ prox,
                           float* __restrict__ out_aux) {
  if (threadIdx.x == 0) {
    float s = 0.0f;
    for (int i = 0; i < B_ * 2; ++i)
      s += (dens[i] * (1.0f / T_)) * (prox[i] * (1.0f / T_));
    out_aux[0] = s * ((float)(2 * 2) / (B_ * 2));   // * E*E / (B*E)
  }
}

// ---------------------------------------------------------------------------
extern "C" void kernel_launch(void* const* d_in, const int* in_sizes, int n_in,
                              void* d_out, int out_size, void* d_ws, size_t ws_size,
                              hipStream_t stream) {
  const float* x     = (const float*)d_in[0];
  const float* ln1_w = (const float*)d_in[1];
  const float* ln1_b = (const float*)d_in[2];
  const float* wqkv  = (const float*)d_in[3];
  const float* bqkv  = (const float*)d_in[4];
  const float* wproj = (const float*)d_in[5];
  const float* bproj = (const float*)d_in[6];
  const float* ln2_w = (const float*)d_in[7];
  const float* ln2_b = (const float*)d_in[8];
  const float* wg    = (const float*)d_in[9];
  const float* w1    = (const float*)d_in[10];
  const float* w2    = (const float*)d_in[11];
  const float* w3    = (const float*)d_in[12];
  float* out = (float*)d_out;
  float* ws  = (float*)d_ws;

  // workspace layout (floats); region1 is reused across phases
  float* h       = ws;                                   // BT*C
  float* region1 = ws + (size_t)BT_ * C_;                // BT*4C
  float* qkvb    = region1;                              // BT*3C
  float* yb      = region1 + (size_t)BT_ * C3_;          // BT*C
  float* hh1     = region1;                              // MCH*FF
  float* hh2     = region1 + (size_t)MCH_ * FF_;         // MCH*FF
  float* eo      = ws + (size_t)BT_ * C_ + (size_t)BT_ * 4 * C_;  // MCH*C
  float* gates   = eo + (size_t)MCH_ * C_;               // BT*2
  float* dens    = gates + (size_t)BT_ * 2;              // 32
  float* prox    = dens + 32;                            // 32

  hipMemsetAsync(dens, 0, 64 * sizeof(float), stream);

  // ---- attention path ----
  ln_kernel<<<BT_, 256, 0, stream>>>(x, ln1_w, ln1_b, h);
  gemm_f32<0, true, false><<<dim3(C3_ / 128, BT_ / 128), 256, 0, stream>>>(
      h, wqkv, bqkv, nullptr, qkvb, BT_, C3_, C_);
  attn_kernel<<<dim3(T_ / 32, B_ * H_), 256, 0, stream>>>(qkvb, yb);
  gemm_f32<0, true, true><<<dim3(C_ / 128, BT_ / 128), 256, 0, stream>>>(
      yb, wproj, bproj, x, out, BT_, C_, C_);

  // ---- MoE path (dense: every token hits both experts; capacity never binds) ----
  ln_kernel<<<BT_, 256, 0, stream>>>(out, ln2_w, ln2_b, h);   // h2 reuses h
  gate_kernel<<<BT_ / 4, 256, 0, stream>>>(h, wg, gates, dens, prox);

  for (int e = 0; e < 2; ++e) {
    const float* w1e = w1 + (size_t)e * C_ * FF_;
    const float* w2e = w2 + (size_t)e * FF_ * FF_;
    const float* w3e = w3 + (size_t)e * FF_ * C_;
    for (int c = 0; c < BT_ / MCH_; ++c) {
      const float* a = h + (size_t)c * MCH_ * C_;
      gemm_f32<1, false, false><<<dim3(FF_ / 128, MCH_ / 128), 256, 0, stream>>>(
          a, w1e, nullptr, nullptr, hh1, MCH_, FF_, C_);
      gemm_f32<1, false, false><<<dim3(FF_ / 128, MCH_ / 128), 256, 0, stream>>>(
          hh1, w2e, nullptr, nullptr, hh2, MCH_, FF_, FF_);
      gemm_f32<0, false, false><<<dim3(C_ / 128, MCH_ / 128), 256, 0, stream>>>(
          hh2, w3e, nullptr, nullptr, eo, MCH_, C_, FF_);
      combine_kernel<<<(MCH_ * C_ / 4) / 256, 256, 0, stream>>>(out, eo, gates,
                                                               c * MCH_, e);
    }
  }

  aux_kernel<<<1, 64, 0, stream>>>(dens, prox, out + (size_t)BT_ * C_);
}

// Round 2
// 2996.850 us; speedup vs baseline: 5.5942x; 5.5942x over previous
//
#include <hip/hip_runtime.h>
#include <cstdint>
#include <cstddef>

// Problem constants (fixed by setup_inputs)
constexpr int B_  = 16;
constexpr int T_  = 1024;
constexpr int C_  = 768;
constexpr int H_  = 12;
constexpr int HD_ = 64;
constexpr int BT_ = B_ * T_;      // 16384
constexpr int C3_ = 3 * C_;       // 2304
constexpr int FF_ = 4 * C_;       // 3072
constexpr int MCH_ = 8192;        // MoE row chunk

typedef __bf16 bf16x8 __attribute__((ext_vector_type(8)));
typedef float  floatx4 __attribute__((ext_vector_type(4)));
typedef unsigned short u16x8 __attribute__((ext_vector_type(8)));

__device__ inline float bf2f(unsigned short u) {
  union { unsigned int i; float f; } x; x.i = ((unsigned int)u) << 16; return x.f;
}
__device__ inline unsigned short f2bf(float f) {
  union { float f; unsigned int i; } x; x.f = f;
  unsigned int u = x.i;
  u += 0x7fffu + ((u >> 16) & 1u);   // round-to-nearest-even
  return (unsigned short)(u >> 16);
}

// async global->LDS, 16B per lane, LDS dest = wave-uniform base + lane*16
#define GLOAD_LDS16(gp, lp)                                              \
  __builtin_amdgcn_global_load_lds(                                      \
      (__attribute__((address_space(1))) void*)(gp),                     \
      (__attribute__((address_space(3))) void*)(lp), 16, 0, 0)

// ---------------------------------------------------------------------------
// LayerNorm: one block (256 threads) per row of 768. f32 in, bf16 out.
// ---------------------------------------------------------------------------
__launch_bounds__(256)
__global__ void ln_kernel(const float* __restrict__ x, const float* __restrict__ w,
                          const float* __restrict__ b, unsigned short* __restrict__ out) {
  int row = blockIdx.x;
  int tid = threadIdx.x;
  const float* xr = x + (size_t)row * C_;
  float v0 = xr[tid], v1 = xr[tid + 256], v2 = xr[tid + 512];
  float s  = v0 + v1 + v2;
  float ss = v0 * v0 + v1 * v1 + v2 * v2;
#pragma unroll
  for (int off = 32; off > 0; off >>= 1) {
    s  += __shfl_down(s, off, 64);
    ss += __shfl_down(ss, off, 64);
  }
  __shared__ float red[8];
  int wid = tid >> 6;
  if ((tid & 63) == 0) { red[wid] = s; red[4 + wid] = ss; }
  __syncthreads();
  float st  = red[0] + red[1] + red[2] + red[3];
  float sst = red[4] + red[5] + red[6] + red[7];
  float mean = st * (1.0f / C_);
  float var  = sst * (1.0f / C_) - mean * mean;
  float rstd = rsqrtf(var + 1e-5f);
  unsigned short* orow = out + (size_t)row * C_;
  orow[tid]       = f2bf((v0 - mean) * rstd * w[tid]       + b[tid]);
  orow[tid + 256] = f2bf((v1 - mean) * rstd * w[tid + 256] + b[tid + 256]);
  orow[tid + 512] = f2bf((v2 - mean) * rstd * w[tid + 512] + b[tid + 512]);
}

// ---------------------------------------------------------------------------
// Transpose+convert: in f32 [K,N] row-major -> out bf16 [N,K] row-major.
// K,N multiples of 32. 256 threads, 32x32 tile.
// ---------------------------------------------------------------------------
__launch_bounds__(256)
__global__ void convT(const float* __restrict__ in, unsigned short* __restrict__ out,
                      int K, int N) {
  __shared__ float t[32][33];
  int n0 = blockIdx.x * 32, k0 = blockIdx.y * 32;
  int tx = threadIdx.x & 31, ty = threadIdx.x >> 5;  // 8 rows per pass
#pragma unroll
  for (int r = 0; r < 32; r += 8)
    t[r + ty][tx] = in[(size_t)(k0 + r + ty) * N + n0 + tx];
  __syncthreads();
#pragma unroll
  for (int r = 0; r < 32; r += 8)
    out[(size_t)(n0 + r + ty) * K + k0 + tx] = f2bf(t[tx][r + ty]);
}

// ---------------------------------------------------------------------------
// bf16 MFMA GEMM: C = post(A @ Bt^T).  A[M,K] bf16, Bt[N,K] bf16 (pre-transposed).
// 128x128 tile / 256 threads (4 waves, each 64x64 via 4x4 of 16x16x32 MFMA).
// BK=64; global_load_lds(16B) staging; XOR-swizzled 16B granules in LDS.
// ACT: 0=none, 1=leaky-relu(0.01).  COMBINE: Cout(f32) += gates2[2*row+eidx]*v.
// ---------------------------------------------------------------------------
template <int ACT, bool BIAS, bool RES, bool COMBINE, bool OUTBF16>
__launch_bounds__(256)
__global__ void gemm_bf16(const unsigned short* __restrict__ A,
                          const unsigned short* __restrict__ Bt,
                          const float* __restrict__ bias,
                          const float* __restrict__ Rres,
                          const float* __restrict__ gates2, int eidx,
                          void* __restrict__ Cout,
                          int M, int N, int K) {
  // 128 rows x 8 granules x 8 bf16 = 16KB each
  __shared__ __attribute__((aligned(16))) unsigned short Als[8192];
  __shared__ __attribute__((aligned(16))) unsigned short Bls[8192];
  const int tid  = threadIdx.x;
  const int wave = tid >> 6, lane = tid & 63;
  const int wr = wave >> 1, wc = wave & 1;
  const int m0 = blockIdx.y * 128, n0 = blockIdx.x * 128;

  // staging: wave w stages rows w*32..w*32+31 of both tiles (4 insts each)
  const int srow = wave * 32 + (lane >> 3);
  const int skg  = (lane & 7) ^ ((lane >> 3) & 7);   // swizzled k-granule
  const unsigned short* Ap = A  + (size_t)(m0 + srow) * K + skg * 8;
  const unsigned short* Bp = Bt + (size_t)(n0 + srow) * K + skg * 8;
  unsigned short* AlsW = Als + wave * 2048;
  unsigned short* BlsW = Bls + wave * 2048;

  floatx4 acc[4][4];
#pragma unroll
  for (int i = 0; i < 4; ++i)
#pragma unroll
    for (int j = 0; j < 4; ++j) acc[i][j] = floatx4{0.f, 0.f, 0.f, 0.f};

  const int q  = lane >> 4;      // quad 0..3
  const int ml = lane & 15;      // m/n within 16-tile
  const int rsw = ml & 7;        // row&7 for swizzle

  for (int k0 = 0; k0 < K; k0 += 64) {
    __syncthreads();
#pragma unroll
    for (int i = 0; i < 4; ++i) {
      GLOAD_LDS16(Ap + (size_t)(i * 8) * K + k0, AlsW + i * 512);
      GLOAD_LDS16(Bp + (size_t)(i * 8) * K + k0, BlsW + i * 512);
    }
    __syncthreads();
#pragma unroll
    for (int ks = 0; ks < 2; ++ks) {
      const int p = (ks * 4 + q) ^ rsw;   // physical granule within row
      bf16x8 af[4], bfg[4];
#pragma unroll
      for (int i = 0; i < 4; ++i) {
        int ar = wr * 64 + i * 16 + ml;
        af[i]  = *(const bf16x8*)&Als[(ar * 8 + p) * 8];
        int br = wc * 64 + i * 16 + ml;
        bfg[i] = *(const bf16x8*)&Bls[(br * 8 + p) * 8];
      }
#pragma unroll
      for (int i = 0; i < 4; ++i)
#pragma unroll
        for (int j = 0; j < 4; ++j)
          acc[i][j] = __builtin_amdgcn_mfma_f32_16x16x32_bf16(af[i], bfg[j], acc[i][j], 0, 0, 0);
    }
  }

  const int rbase = q * 4;
#pragma unroll
  for (int i = 0; i < 4; ++i) {
    int row = m0 + wr * 64 + i * 16 + rbase;
#pragma unroll
    for (int j = 0; j < 4; ++j) {
      int col = n0 + wc * 64 + j * 16 + ml;
      float bcol = BIAS ? bias[col] : 0.f;
#pragma unroll
      for (int r = 0; r < 4; ++r) {
        float v = acc[i][j][r];
        if (BIAS) v += bcol;
        if (ACT == 1) v = (v >= 0.f) ? v : 0.01f * v;
        if (RES) v += Rres[(size_t)(row + r) * N + col];
        if (COMBINE) {
          float g = gates2[2 * (row + r) + eidx];
          float* op = (float*)Cout + (size_t)(row + r) * N + col;
          *op += g * v;
        } else if (OUTBF16) {
          ((unsigned short*)Cout)[(size_t)(row + r) * N + col] = f2bf(v);
        } else {
          ((float*)Cout)[(size_t)(row + r) * N + col] = v;
        }
      }
    }
  }
}

// ---------------------------------------------------------------------------
// Flash-style causal attention. qkv: [B*T, 3C] bf16. y out: [B*T, C] bf16.
// f32 internals. Block: 256 threads = 32 q-rows x 8 lanes; K-tiles of 64.
// ---------------------------------------------------------------------------
__launch_bounds__(256)
__global__ void attn_kernel(const unsigned short* __restrict__ qkv,
                            unsigned short* __restrict__ y) {
  __shared__ float Qs[32][68];
  __shared__ float KsT[64][68];
  __shared__ float Vs[64][68];
  __shared__ float Ps[32][65];
  int tid = threadIdx.x;
  int tx = tid & 7;
  int ty = tid >> 3;
  int q0 = blockIdx.x * 32;
  int bh = blockIdx.y;
  int b = bh / H_, h = bh % H_;
  const size_t base = (size_t)b * T_ * C3_ + (size_t)h * HD_;

  {  // load Q tile (bf16 -> f32), pre-scaled by 1/sqrt(hd)
    const unsigned short* src = qkv + base + (size_t)(q0 + ty) * C3_ + tx * 8;
    u16x8 qv = *(const u16x8*)src;
#pragma unroll
    for (int t = 0; t < 8; ++t) Qs[ty][tx * 8 + t] = bf2f(qv[t]) * 0.125f;
  }

  float O[8] = {0, 0, 0, 0, 0, 0, 0, 0};
  float mrow = -1e30f, lrow = 0.0f;
  int nkt = (q0 + 95) >> 6;
  int lr = tid >> 2;
  int lc = (tid & 3) << 4;

  for (int kt = 0; kt < nkt; ++kt) {
    int k0 = kt << 6;
    __syncthreads();
    {
      const unsigned short* kp = qkv + base + (size_t)(k0 + lr) * C3_ + C_ + lc;
      const unsigned short* vp = kp + C_;
      u16x8 ka = *(const u16x8*)kp;
      u16x8 kb = *(const u16x8*)(kp + 8);
      u16x8 va = *(const u16x8*)vp;
      u16x8 vb = *(const u16x8*)(vp + 8);
#pragma unroll
      for (int t = 0; t < 8; ++t) {
        KsT[lc + t][lr]     = bf2f(ka[t]);
        KsT[lc + 8 + t][lr] = bf2f(kb[t]);
        Vs[lr][lc + t]      = bf2f(va[t]);
        Vs[lr][lc + 8 + t]  = bf2f(vb[t]);
      }
    }
    __syncthreads();

    float s[8] = {0, 0, 0, 0, 0, 0, 0, 0};
#pragma unroll
    for (int d = 0; d < 64; ++d) {
      float qd = Qs[ty][d];
      float4 k0v = *(const float4*)&KsT[d][tx * 8];
      float4 k1v = *(const float4*)&KsT[d][tx * 8 + 4];
      s[0] += qd * k0v.x; s[1] += qd * k0v.y; s[2] += qd * k0v.z; s[3] += qd * k0v.w;
      s[4] += qd * k1v.x; s[5] += qd * k1v.y; s[6] += qd * k1v.z; s[7] += qd * k1v.w;
    }
    int qg = q0 + ty;
#pragma unroll
    for (int kk = 0; kk < 8; ++kk)
      if (k0 + tx * 8 + kk > qg) s[kk] = -1e30f;

    float tmax = s[0];
#pragma unroll
    for (int kk = 1; kk < 8; ++kk) tmax = fmaxf(tmax, s[kk]);
    tmax = fmaxf(tmax, __shfl_xor(tmax, 1, 64));
    tmax = fmaxf(tmax, __shfl_xor(tmax, 2, 64));
    tmax = fmaxf(tmax, __shfl_xor(tmax, 4, 64));
    float mnew  = fmaxf(mrow, tmax);
    float alpha = __expf(mrow - mnew);
    float psum = 0.0f;
#pragma unroll
    for (int kk = 0; kk < 8; ++kk) {
      float p = __expf(s[kk] - mnew);
      Ps[ty][tx * 8 + kk] = p;
      psum += p;
    }
    psum += __shfl_xor(psum, 1, 64);
    psum += __shfl_xor(psum, 2, 64);
    psum += __shfl_xor(psum, 4, 64);
    lrow = lrow * alpha + psum;
    mrow = mnew;
#pragma unroll
    for (int i = 0; i < 8; ++i) O[i] *= alpha;
#pragma unroll
    for (int kk = 0; kk < 64; ++kk) {
      float p = Ps[ty][kk];
      float4 v0 = *(const float4*)&Vs[kk][tx * 8];
      float4 v1 = *(const float4*)&Vs[kk][tx * 8 + 4];
      O[0] += p * v0.x; O[1] += p * v0.y; O[2] += p * v0.z; O[3] += p * v0.w;
      O[4] += p * v1.x; O[5] += p * v1.y; O[6] += p * v1.z; O[7] += p * v1.w;
    }
  }

  float inv = 1.0f / lrow;
  unsigned short* dst = y + ((size_t)b * T_ + q0 + ty) * C_ + h * HD_ + tx * 8;
  u16x8 ov;
#pragma unroll
  for (int t = 0; t < 8; ++t) ov[t] = f2bf(O[t] * inv);
  *(u16x8*)dst = ov;
}

// ---------------------------------------------------------------------------
// Gating: one wave per token; h2 is bf16.
// ---------------------------------------------------------------------------
__launch_bounds__(256)
__global__ void gate_kernel(const unsigned short* __restrict__ h2, const float* __restrict__ wg,
                            float* __restrict__ gates, float* __restrict__ dens,
                            float* __restrict__ prox) {
  int wave = threadIdx.x >> 6, lane = threadIdx.x & 63;
  int t = blockIdx.x * 4 + wave;
  const unsigned short* hr = h2 + (size_t)t * C_;
  float a0 = 0.0f, a1 = 0.0f;
#pragma unroll
  for (int i = 0; i < 12; ++i) {
    int d = lane + 64 * i;
    float hv = bf2f(hr[d]);
    a0 += hv * wg[2 * d];
    a1 += hv * wg[2 * d + 1];
  }
#pragma unroll
  for (int off = 32; off > 0; off >>= 1) {
    a0 += __shfl_down(a0, off, 64);
    a1 += __shfl_down(a1, off, 64);
  }
  if (lane == 0) {
    float m  = fmaxf(a0, a1);
    float e0 = __expf(a0 - m), e1 = __expf(a1 - m);
    float invs = 1.0f / (e0 + e1);
    float p0 = e0 * invs, p1 = e1 * invs;
    const float gnorm = 1.0f / (1.0f + 1e-9f);
    gates[2 * t]     = p0 * gnorm;
    gates[2 * t + 1] = p1 * gnorm;
    int bidx = t >> 10;
    int idx1 = (p1 > p0) ? 1 : 0;
    atomicAdd(&dens[bidx * 2 + idx1], 1.0f);
    atomicAdd(&prox[bidx * 2 + 0], p0);
    atomicAdd(&prox[bidx * 2 + 1], p1);
  }
}

// ---------------------------------------------------------------------------
__global__ void aux_kernel(const float* __restrict__ dens, const float* __restrict__ prox,
                           float* __restrict__ out_aux) {
  if (threadIdx.x == 0) {
    float s = 0.0f;
    for (int i = 0; i < B_ * 2; ++i)
      s += (dens[i] * (1.0f / T_)) * (prox[i] * (1.0f / T_));
    out_aux[0] = s * ((float)(2 * 2) / (B_ * 2));
  }
}

// ---------------------------------------------------------------------------
extern "C" void kernel_launch(void* const* d_in, const int* in_sizes, int n_in,
                              void* d_out, int out_size, void* d_ws, size_t ws_size,
                              hipStream_t stream) {
  const float* x     = (const float*)d_in[0];
  const float* ln1_w = (const float*)d_in[1];
  const float* ln1_b = (const float*)d_in[2];
  const float* wqkv  = (const float*)d_in[3];
  const float* bqkv  = (const float*)d_in[4];
  const float* wproj = (const float*)d_in[5];
  const float* bproj = (const float*)d_in[6];
  const float* ln2_w = (const float*)d_in[7];
  const float* ln2_b = (const float*)d_in[8];
  const float* wg    = (const float*)d_in[9];
  const float* w1    = (const float*)d_in[10];
  const float* w2    = (const float*)d_in[11];
  const float* w3    = (const float*)d_in[12];
  float* out = (float*)d_out;

  // workspace layout (ushort units)
  unsigned short* wsu   = (unsigned short*)d_ws;
  unsigned short* wqkvT = wsu;                                   // 2304*768
  unsigned short* wprojT= wqkvT + (size_t)C3_ * C_;              // 768*768
  unsigned short* w1T   = wprojT + (size_t)C_ * C_;              // 2*3072*768
  unsigned short* w2T   = w1T + (size_t)2 * FF_ * C_;            // 2*3072*3072
  unsigned short* w3T   = w2T + (size_t)2 * FF_ * FF_;           // 2*768*3072
  unsigned short* hb    = w3T + (size_t)2 * C_ * FF_;            // BT*C
  unsigned short* region= hb + (size_t)BT_ * C_;                 // BT*4C (union)
  unsigned short* qkvb  = region;                                // BT*3C
  unsigned short* yb    = region + (size_t)BT_ * C3_;            // BT*C
  unsigned short* hh1   = region;                                // MCH*FF
  unsigned short* hh2   = region + (size_t)MCH_ * FF_;           // MCH*FF
  float* gates = (float*)(region + (size_t)BT_ * 4 * C_);        // BT*2
  float* dens  = gates + (size_t)BT_ * 2;                        // 32
  float* prox  = dens + 32;                                      // 32

  hipMemsetAsync(dens, 0, 64 * sizeof(float), stream);

  // ---- weight transpose+convert (per launch; ~60MB, memory-bound, tiny) ----
  convT<<<dim3(C3_ / 32, C_ / 32), 256, 0, stream>>>(wqkv, wqkvT, C_, C3_);
  convT<<<dim3(C_ / 32, C_ / 32), 256, 0, stream>>>(wproj, wprojT, C_, C_);
  for (int e = 0; e < 2; ++e) {
    convT<<<dim3(FF_ / 32, C_ / 32), 256, 0, stream>>>(
        w1 + (size_t)e * C_ * FF_, w1T + (size_t)e * FF_ * C_, C_, FF_);
    convT<<<dim3(FF_ / 32, FF_ / 32), 256, 0, stream>>>(
        w2 + (size_t)e * FF_ * FF_, w2T + (size_t)e * FF_ * FF_, FF_, FF_);
    convT<<<dim3(C_ / 32, FF_ / 32), 256, 0, stream>>>(
        w3 + (size_t)e * FF_ * C_, w3T + (size_t)e * C_ * FF_, FF_, C_);
  }

  // ---- attention path ----
  ln_kernel<<<BT_, 256, 0, stream>>>(x, ln1_w, ln1_b, hb);
  gemm_bf16<0, true, false, false, true><<<dim3(C3_ / 128, BT_ / 128), 256, 0, stream>>>(
      hb, wqkvT, bqkv, nullptr, nullptr, 0, qkvb, BT_, C3_, C_);
  attn_kernel<<<dim3(T_ / 32, B_ * H_), 256, 0, stream>>>(qkvb, yb);
  gemm_bf16<0, true, true, false, false><<<dim3(C_ / 128, BT_ / 128), 256, 0, stream>>>(
      yb, wprojT, bproj, x, nullptr, 0, out, BT_, C_, C_);

  // ---- MoE path (dense: E=2 top-2 -> every token hits both experts) ----
  ln_kernel<<<BT_, 256, 0, stream>>>(out, ln2_w, ln2_b, hb);
  gate_kernel<<<BT_ / 4, 256, 0, stream>>>(hb, wg, gates, dens, prox);

  for (int e = 0; e < 2; ++e) {
    for (int c = 0; c < BT_ / MCH_; ++c) {
      const unsigned short* a = hb + (size_t)c * MCH_ * C_;
      gemm_bf16<1, false, false, false, true><<<dim3(FF_ / 128, MCH_ / 128), 256, 0, stream>>>(
          a, w1T + (size_t)e * FF_ * C_, nullptr, nullptr, nullptr, 0, hh1, MCH_, FF_, C_);
      gemm_bf16<1, false, false, false, true><<<dim3(FF_ / 128, MCH_ / 128), 256, 0, stream>>>(
          hh1, w2T + (size_t)e * FF_ * FF_, nullptr, nullptr, nullptr, 0, hh2, MCH_, FF_, FF_);
      gemm_bf16<0, false, false, true, false><<<dim3(C_ / 128, MCH_ / 128), 256, 0, stream>>>(
          hh2, w3T + (size_t)e * C_ * FF_, nullptr, nullptr,
          gates + (size_t)2 * c * MCH_, e, out + (size_t)c * MCH_ * C_, MCH_, C_, FF_);
    }
  }

  aux_kernel<<<1, 64, 0, stream>>>(dens, prox, out + (size_t)BT_ * C_);
}

// Round 3
// 2144.896 us; speedup vs baseline: 7.8162x; 1.3972x over previous
//
#include <hip/hip_runtime.h>
#include <cstdint>
#include <cstddef>

// Problem constants (fixed by setup_inputs)
constexpr int B_  = 16;
constexpr int T_  = 1024;
constexpr int C_  = 768;
constexpr int H_  = 12;
constexpr int HD_ = 64;
constexpr int BT_ = B_ * T_;      // 16384
constexpr int C3_ = 3 * C_;       // 2304
constexpr int FF_ = 4 * C_;       // 3072
constexpr int MCH_ = 8192;        // MoE row chunk

typedef __bf16 bf16x8 __attribute__((ext_vector_type(8)));
typedef float  floatx4 __attribute__((ext_vector_type(4)));
typedef unsigned short u16x8 __attribute__((ext_vector_type(8)));

__device__ inline float bf2f(unsigned short u) {
  union { unsigned int i; float f; } x; x.i = ((unsigned int)u) << 16; return x.f;
}
__device__ inline unsigned short f2bf(float f) {
  union { float f; unsigned int i; } x; x.f = f;
  unsigned int u = x.i;
  u += 0x7fffu + ((u >> 16) & 1u);   // round-to-nearest-even
  return (unsigned short)(u >> 16);
}

// async global->LDS, 16B per lane, LDS dest = wave-uniform base + lane*16
#define GLOAD_LDS16(gp, lp)                                              \
  __builtin_amdgcn_global_load_lds(                                      \
      (__attribute__((address_space(1))) void*)(gp),                     \
      (__attribute__((address_space(3))) void*)(lp), 16, 0, 0)

// ---------------------------------------------------------------------------
// LayerNorm: one block (256 threads) per row of 768. f32 in, bf16 out.
// ---------------------------------------------------------------------------
__launch_bounds__(256)
__global__ void ln_kernel(const float* __restrict__ x, const float* __restrict__ w,
                          const float* __restrict__ b, unsigned short* __restrict__ out) {
  int row = blockIdx.x;
  int tid = threadIdx.x;
  const float* xr = x + (size_t)row * C_;
  float v0 = xr[tid], v1 = xr[tid + 256], v2 = xr[tid + 512];
  float s  = v0 + v1 + v2;
  float ss = v0 * v0 + v1 * v1 + v2 * v2;
#pragma unroll
  for (int off = 32; off > 0; off >>= 1) {
    s  += __shfl_down(s, off, 64);
    ss += __shfl_down(ss, off, 64);
  }
  __shared__ float red[8];
  int wid = tid >> 6;
  if ((tid & 63) == 0) { red[wid] = s; red[4 + wid] = ss; }
  __syncthreads();
  float st  = red[0] + red[1] + red[2] + red[3];
  float sst = red[4] + red[5] + red[6] + red[7];
  float mean = st * (1.0f / C_);
  float var  = sst * (1.0f / C_) - mean * mean;
  float rstd = rsqrtf(var + 1e-5f);
  unsigned short* orow = out + (size_t)row * C_;
  orow[tid]       = f2bf((v0 - mean) * rstd * w[tid]       + b[tid]);
  orow[tid + 256] = f2bf((v1 - mean) * rstd * w[tid + 256] + b[tid + 256]);
  orow[tid + 512] = f2bf((v2 - mean) * rstd * w[tid + 512] + b[tid + 512]);
}

// ---------------------------------------------------------------------------
// Transpose+convert: in f32 [K,N] row-major -> out bf16 [N,K] row-major.
// ---------------------------------------------------------------------------
__launch_bounds__(256)
__global__ void convT(const float* __restrict__ in, unsigned short* __restrict__ out,
                      int K, int N) {
  __shared__ float t[32][33];
  int n0 = blockIdx.x * 32, k0 = blockIdx.y * 32;
  int tx = threadIdx.x & 31, ty = threadIdx.x >> 5;  // 8 rows per pass
#pragma unroll
  for (int r = 0; r < 32; r += 8)
    t[r + ty][tx] = in[(size_t)(k0 + r + ty) * N + n0 + tx];
  __syncthreads();
#pragma unroll
  for (int r = 0; r < 32; r += 8)
    out[(size_t)(n0 + r + ty) * K + k0 + tx] = f2bf(t[tx][r + ty]);
}

// ---------------------------------------------------------------------------
// bf16 MFMA GEMM: C = post(A @ Bt^T).  A[M,K] bf16, Bt[N,K] bf16 (pre-transposed).
// 128x128 tile / 256 threads (4 waves, each 64x64 via 4x4 of 16x16x32 MFMA).
// ---------------------------------------------------------------------------
template <int ACT, bool BIAS, bool RES, bool COMBINE, bool OUTBF16>
__launch_bounds__(256)
__global__ void gemm_bf16(const unsigned short* __restrict__ A,
                          const unsigned short* __restrict__ Bt,
                          const float* __restrict__ bias,
                          const float* __restrict__ Rres,
                          const float* __restrict__ gates2, int eidx,
                          void* __restrict__ Cout,
                          int M, int N, int K) {
  __shared__ __attribute__((aligned(16))) unsigned short Als[8192];
  __shared__ __attribute__((aligned(16))) unsigned short Bls[8192];
  const int tid  = threadIdx.x;
  const int wave = tid >> 6, lane = tid & 63;
  const int wr = wave >> 1, wc = wave & 1;
  const int m0 = blockIdx.y * 128, n0 = blockIdx.x * 128;

  const int srow = wave * 32 + (lane >> 3);
  const int skg  = (lane & 7) ^ ((lane >> 3) & 7);   // swizzled k-granule
  const unsigned short* Ap = A  + (size_t)(m0 + srow) * K + skg * 8;
  const unsigned short* Bp = Bt + (size_t)(n0 + srow) * K + skg * 8;
  unsigned short* AlsW = Als + wave * 2048;
  unsigned short* BlsW = Bls + wave * 2048;

  floatx4 acc[4][4];
#pragma unroll
  for (int i = 0; i < 4; ++i)
#pragma unroll
    for (int j = 0; j < 4; ++j) acc[i][j] = floatx4{0.f, 0.f, 0.f, 0.f};

  const int q  = lane >> 4;
  const int ml = lane & 15;
  const int rsw = ml & 7;

  for (int k0 = 0; k0 < K; k0 += 64) {
    __syncthreads();
#pragma unroll
    for (int i = 0; i < 4; ++i) {
      GLOAD_LDS16(Ap + (size_t)(i * 8) * K + k0, AlsW + i * 512);
      GLOAD_LDS16(Bp + (size_t)(i * 8) * K + k0, BlsW + i * 512);
    }
    __syncthreads();
#pragma unroll
    for (int ks = 0; ks < 2; ++ks) {
      const int p = (ks * 4 + q) ^ rsw;
      bf16x8 af[4], bfg[4];
#pragma unroll
      for (int i = 0; i < 4; ++i) {
        int ar = wr * 64 + i * 16 + ml;
        af[i]  = *(const bf16x8*)&Als[(ar * 8 + p) * 8];
        int br = wc * 64 + i * 16 + ml;
        bfg[i] = *(const bf16x8*)&Bls[(br * 8 + p) * 8];
      }
#pragma unroll
      for (int i = 0; i < 4; ++i)
#pragma unroll
        for (int j = 0; j < 4; ++j)
          acc[i][j] = __builtin_amdgcn_mfma_f32_16x16x32_bf16(af[i], bfg[j], acc[i][j], 0, 0, 0);
    }
  }

  const int rbase = q * 4;
#pragma unroll
  for (int i = 0; i < 4; ++i) {
    int row = m0 + wr * 64 + i * 16 + rbase;
#pragma unroll
    for (int j = 0; j < 4; ++j) {
      int col = n0 + wc * 64 + j * 16 + ml;
      float bcol = BIAS ? bias[col] : 0.f;
#pragma unroll
      for (int r = 0; r < 4; ++r) {
        float v = acc[i][j][r];
        if (BIAS) v += bcol;
        if (ACT == 1) v = (v >= 0.f) ? v : 0.01f * v;
        if (RES) v += Rres[(size_t)(row + r) * N + col];
        if (COMBINE) {
          float g = gates2[2 * (row + r) + eidx];
          float* op = (float*)Cout + (size_t)(row + r) * N + col;
          *op += g * v;
        } else if (OUTBF16) {
          ((unsigned short*)Cout)[(size_t)(row + r) * N + col] = f2bf(v);
        } else {
          ((float*)Cout)[(size_t)(row + r) * N + col] = v;
        }
      }
    }
  }
}

// ---------------------------------------------------------------------------
// MFMA flash attention. qkv: [B*T, 3C] bf16 (q|k|v, col = h*64+d). y: bf16.
// Block = 64 q-rows of one (b,h); 4 waves, wave w owns rows w*16..w*16+15.
// K-tiles of 64 keys. S via 16x16x32 bf16 MFMA; P through wave-private LDS;
// V transpose-staged so PV B-frags are contiguous b128 reads.
// ---------------------------------------------------------------------------
__launch_bounds__(256)
__global__ void attn_kernel(const unsigned short* __restrict__ qkv,
                            unsigned short* __restrict__ y) {
  __shared__ __attribute__((aligned(16))) unsigned short Qls[64 * 64];  // [row][slot]
  __shared__ __attribute__((aligned(16))) unsigned short Kls[64 * 64];  // [key][slot]
  __shared__ __attribute__((aligned(16))) unsigned short Vt[64 * 72];   // [d][key] pad
  __shared__ __attribute__((aligned(16))) unsigned short Pls[4 * 16 * 72];

  const int tid  = threadIdx.x;
  const int wave = tid >> 6, lane = tid & 63;
  const int quad = lane >> 4, n = lane & 15;
  const int q0 = blockIdx.x * 64;
  const int bh = blockIdx.y;
  const int b = bh / H_, h = bh % H_;
  const size_t base = (size_t)b * T_ * C3_ + (size_t)h * HD_;

  // stage Q once: wave w stages rows w*16..w*16+15 (XOR-swizzled granules)
  {
    const int r8 = lane >> 3;            // 0..7
    const int g  = (lane & 7) ^ r8;      // global granule for LDS slot lane&7
#pragma unroll
    for (int i = 0; i < 2; ++i) {
      int row = wave * 16 + i * 8 + r8;
      GLOAD_LDS16(qkv + base + (size_t)(q0 + row) * C3_ + g * 8,
                  Qls + wave * 1024 + i * 512);
    }
  }

  floatx4 O[4];
#pragma unroll
  for (int ct = 0; ct < 4; ++ct) O[ct] = floatx4{0.f, 0.f, 0.f, 0.f};
  float mrow[4] = {-1e30f, -1e30f, -1e30f, -1e30f};
  float lrow[4] = {0.f, 0.f, 0.f, 0.f};

  const int nkt = blockIdx.x + 1;
  unsigned short* Pw = Pls + wave * (16 * 72);

  for (int kt = 0; kt < nkt; ++kt) {
    const int k0 = kt << 6;
    __syncthreads();   // previous tile fully consumed
    {  // stage K (swizzled, via DMA)
      const int r8 = lane >> 3;
      const int g  = (lane & 7) ^ r8;
#pragma unroll
      for (int i = 0; i < 2; ++i) {
        int key = wave * 16 + i * 8 + r8;
        GLOAD_LDS16(qkv + base + (size_t)(k0 + key) * C3_ + C_ + g * 8,
                    Kls + wave * 1024 + i * 512);
      }
    }
    {  // stage V transposed: Vt[d][key]
      int key = tid & 63;
      int dbase = (tid >> 6) * 8;
#pragma unroll
      for (int it = 0; it < 2; ++it) {
        int d0 = dbase + it * 32;
        u16x8 vv = *(const u16x8*)(qkv + base + (size_t)(k0 + key) * C3_ + 2 * C_ + d0);
#pragma unroll
        for (int j = 0; j < 8; ++j) Vt[(d0 + j) * 72 + key] = vv[j];
      }
    }
    __syncthreads();

    // ---- S = Q K^T (rows wave*16..+15, cols k0..k0+63) ----
    floatx4 sacc[4];
#pragma unroll
    for (int ct = 0; ct < 4; ++ct) sacc[ct] = floatx4{0.f, 0.f, 0.f, 0.f};
#pragma unroll
    for (int ks = 0; ks < 2; ++ks) {
      const int ga = (ks * 4 + quad) ^ (n & 7);
      bf16x8 aq = *(const bf16x8*)&Qls[((wave * 16 + n) * 8 + ga) * 8];
#pragma unroll
      for (int ct = 0; ct < 4; ++ct) {
        bf16x8 kb = *(const bf16x8*)&Kls[((ct * 16 + n) * 8 + ga) * 8];
        sacc[ct] = __builtin_amdgcn_mfma_f32_16x16x32_bf16(aq, kb, sacc[ct], 0, 0, 0);
      }
    }

    // ---- online softmax (state in regs; C-layout row = quad*4+r) ----
    float p[4][4];
#pragma unroll
    for (int ct = 0; ct < 4; ++ct)
#pragma unroll
      for (int r = 0; r < 4; ++r) p[ct][r] = sacc[ct][r] * 0.125f;
    if (kt == nkt - 1) {  // diagonal tile: causal mask
      const int kgb = k0 + n, qgb = q0 + wave * 16 + quad * 4;
#pragma unroll
      for (int ct = 0; ct < 4; ++ct)
#pragma unroll
        for (int r = 0; r < 4; ++r)
          if (kgb + ct * 16 > qgb + r) p[ct][r] = -1e30f;
    }
#pragma unroll
    for (int r = 0; r < 4; ++r) {
      float tm = fmaxf(fmaxf(p[0][r], p[1][r]), fmaxf(p[2][r], p[3][r]));
      tm = fmaxf(tm, __shfl_xor(tm, 1, 64));
      tm = fmaxf(tm, __shfl_xor(tm, 2, 64));
      tm = fmaxf(tm, __shfl_xor(tm, 4, 64));
      tm = fmaxf(tm, __shfl_xor(tm, 8, 64));
      float mn = fmaxf(mrow[r], tm);
      float alpha = __expf(mrow[r] - mn);
      mrow[r] = mn;
      float ps = 0.f;
#pragma unroll
      for (int ct = 0; ct < 4; ++ct) {
        float pe = __expf(p[ct][r] - mn);
        p[ct][r] = pe;
        ps += pe;
      }
      ps += __shfl_xor(ps, 1, 64);
      ps += __shfl_xor(ps, 2, 64);
      ps += __shfl_xor(ps, 4, 64);
      ps += __shfl_xor(ps, 8, 64);
      lrow[r] = lrow[r] * alpha + ps;
      O[0][r] *= alpha; O[1][r] *= alpha; O[2][r] *= alpha; O[3][r] *= alpha;
    }

    // ---- P: C-layout -> A-layout via wave-private LDS ----
#pragma unroll
    for (int ct = 0; ct < 4; ++ct)
#pragma unroll
      for (int r = 0; r < 4; ++r)
        Pw[(quad * 4 + r) * 72 + ct * 16 + n] = f2bf(p[ct][r]);

    // ---- O += P V ----
#pragma unroll
    for (int ks = 0; ks < 2; ++ks) {
      bf16x8 pa = *(const bf16x8*)&Pw[n * 72 + (ks * 4 + quad) * 8];
#pragma unroll
      for (int ct = 0; ct < 4; ++ct) {
        bf16x8 vb = *(const bf16x8*)&Vt[(ct * 16 + n) * 72 + (ks * 4 + quad) * 8];
        O[ct] = __builtin_amdgcn_mfma_f32_16x16x32_bf16(pa, vb, O[ct], 0, 0, 0);
      }
    }
  }

  // ---- epilogue ----
#pragma unroll
  for (int r = 0; r < 4; ++r) {
    float inv = 1.0f / lrow[r];
    int row = q0 + wave * 16 + quad * 4 + r;
    unsigned short* dst = y + ((size_t)b * T_ + row) * C_ + h * HD_;
#pragma unroll
    for (int ct = 0; ct < 4; ++ct)
      dst[ct * 16 + n] = f2bf(O[ct][r] * inv);
  }
}

// ---------------------------------------------------------------------------
// Gating: one wave per token; h2 is bf16.
// ---------------------------------------------------------------------------
__launch_bounds__(256)
__global__ void gate_kernel(const unsigned short* __restrict__ h2, const float* __restrict__ wg,
                            float* __restrict__ gates, float* __restrict__ dens,
                            float* __restrict__ prox) {
  int wave = threadIdx.x >> 6, lane = threadIdx.x & 63;
  int t = blockIdx.x * 4 + wave;
  const unsigned short* hr = h2 + (size_t)t * C_;
  float a0 = 0.0f, a1 = 0.0f;
#pragma unroll
  for (int i = 0; i < 12; ++i) {
    int d = lane + 64 * i;
    float hv = bf2f(hr[d]);
    a0 += hv * wg[2 * d];
    a1 += hv * wg[2 * d + 1];
  }
#pragma unroll
  for (int off = 32; off > 0; off >>= 1) {
    a0 += __shfl_down(a0, off, 64);
    a1 += __shfl_down(a1, off, 64);
  }
  if (lane == 0) {
    float m  = fmaxf(a0, a1);
    float e0 = __expf(a0 - m), e1 = __expf(a1 - m);
    float invs = 1.0f / (e0 + e1);
    float p0 = e0 * invs, p1 = e1 * invs;
    const float gnorm = 1.0f / (1.0f + 1e-9f);
    gates[2 * t]     = p0 * gnorm;
    gates[2 * t + 1] = p1 * gnorm;
    int bidx = t >> 10;
    int idx1 = (p1 > p0) ? 1 : 0;
    atomicAdd(&dens[bidx * 2 + idx1], 1.0f);
    atomicAdd(&prox[bidx * 2 + 0], p0);
    atomicAdd(&prox[bidx * 2 + 1], p1);
  }
}

// ---------------------------------------------------------------------------
__global__ void aux_kernel(const float* __restrict__ dens, const float* __restrict__ prox,
                           float* __restrict__ out_aux) {
  if (threadIdx.x == 0) {
    float s = 0.0f;
    for (int i = 0; i < B_ * 2; ++i)
      s += (dens[i] * (1.0f / T_)) * (prox[i] * (1.0f / T_));
    out_aux[0] = s * ((float)(2 * 2) / (B_ * 2));
  }
}

// ---------------------------------------------------------------------------
extern "C" void kernel_launch(void* const* d_in, const int* in_sizes, int n_in,
                              void* d_out, int out_size, void* d_ws, size_t ws_size,
                              hipStream_t stream) {
  const float* x     = (const float*)d_in[0];
  const float* ln1_w = (const float*)d_in[1];
  const float* ln1_b = (const float*)d_in[2];
  const float* wqkv  = (const float*)d_in[3];
  const float* bqkv  = (const float*)d_in[4];
  const float* wproj = (const float*)d_in[5];
  const float* bproj = (const float*)d_in[6];
  const float* ln2_w = (const float*)d_in[7];
  const float* ln2_b = (const float*)d_in[8];
  const float* wg    = (const float*)d_in[9];
  const float* w1    = (const float*)d_in[10];
  const float* w2    = (const float*)d_in[11];
  const float* w3    = (const float*)d_in[12];
  float* out = (float*)d_out;

  // workspace layout (ushort units)
  unsigned short* wsu   = (unsigned short*)d_ws;
  unsigned short* wqkvT = wsu;                                   // 2304*768
  unsigned short* wprojT= wqkvT + (size_t)C3_ * C_;              // 768*768
  unsigned short* w1T   = wprojT + (size_t)C_ * C_;              // 2*3072*768
  unsigned short* w2T   = w1T + (size_t)2 * FF_ * C_;            // 2*3072*3072
  unsigned short* w3T   = w2T + (size_t)2 * FF_ * FF_;           // 2*768*3072
  unsigned short* hb    = w3T + (size_t)2 * C_ * FF_;            // BT*C
  unsigned short* region= hb + (size_t)BT_ * C_;                 // BT*4C (union)
  unsigned short* qkvb  = region;                                // BT*3C
  unsigned short* yb    = region + (size_t)BT_ * C3_;            // BT*C
  unsigned short* hh1   = region;                                // MCH*FF
  unsigned short* hh2   = region + (size_t)MCH_ * FF_;           // MCH*FF
  float* gates = (float*)(region + (size_t)BT_ * 4 * C_);        // BT*2
  float* dens  = gates + (size_t)BT_ * 2;                        // 32
  float* prox  = dens + 32;                                      // 32

  hipMemsetAsync(dens, 0, 64 * sizeof(float), stream);

  // ---- weight transpose+convert ----
  convT<<<dim3(C3_ / 32, C_ / 32), 256, 0, stream>>>(wqkv, wqkvT, C_, C3_);
  convT<<<dim3(C_ / 32, C_ / 32), 256, 0, stream>>>(wproj, wprojT, C_, C_);
  for (int e = 0; e < 2; ++e) {
    convT<<<dim3(FF_ / 32, C_ / 32), 256, 0, stream>>>(
        w1 + (size_t)e * C_ * FF_, w1T + (size_t)e * FF_ * C_, C_, FF_);
    convT<<<dim3(FF_ / 32, FF_ / 32), 256, 0, stream>>>(
        w2 + (size_t)e * FF_ * FF_, w2T + (size_t)e * FF_ * FF_, FF_, FF_);
    convT<<<dim3(C_ / 32, FF_ / 32), 256, 0, stream>>>(
        w3 + (size_t)e * FF_ * C_, w3T + (size_t)e * C_ * FF_, FF_, C_);
  }

  // ---- attention path ----
  ln_kernel<<<BT_, 256, 0, stream>>>(x, ln1_w, ln1_b, hb);
  gemm_bf16<0, true, false, false, true><<<dim3(C3_ / 128, BT_ / 128), 256, 0, stream>>>(
      hb, wqkvT, bqkv, nullptr, nullptr, 0, qkvb, BT_, C3_, C_);
  attn_kernel<<<dim3(T_ / 64, B_ * H_), 256, 0, stream>>>(qkvb, yb);
  gemm_bf16<0, true, true, false, false><<<dim3(C_ / 128, BT_ / 128), 256, 0, stream>>>(
      yb, wprojT, bproj, x, nullptr, 0, out, BT_, C_, C_);

  // ---- MoE path (dense: E=2 top-2 -> every token hits both experts) ----
  ln_kernel<<<BT_, 256, 0, stream>>>(out, ln2_w, ln2_b, hb);
  gate_kernel<<<BT_ / 4, 256, 0, stream>>>(hb, wg, gates, dens, prox);

  for (int e = 0; e < 2; ++e) {
    for (int c = 0; c < BT_ / MCH_; ++c) {
      const unsigned short* a = hb + (size_t)c * MCH_ * C_;
      gemm_bf16<1, false, false, false, true><<<dim3(FF_ / 128, MCH_ / 128), 256, 0, stream>>>(
          a, w1T + (size_t)e * FF_ * C_, nullptr, nullptr, nullptr, 0, hh1, MCH_, FF_, C_);
      gemm_bf16<1, false, false, false, true><<<dim3(FF_ / 128, MCH_ / 128), 256, 0, stream>>>(
          hh1, w2T + (size_t)e * FF_ * FF_, nullptr, nullptr, nullptr, 0, hh2, MCH_, FF_, FF_);
      gemm_bf16<0, false, false, true, false><<<dim3(C_ / 128, MCH_ / 128), 256, 0, stream>>>(
          hh2, w3T + (size_t)e * C_ * FF_, nullptr, nullptr,
          gates + (size_t)2 * c * MCH_, e, out + (size_t)c * MCH_ * C_, MCH_, C_, FF_);
    }
  }

  aux_kernel<<<1, 64, 0, stream>>>(dens, prox, out + (size_t)BT_ * C_);
}

// Round 4
// 1832.942 us; speedup vs baseline: 9.1464x; 1.1702x over previous
//
#include <hip/hip_runtime.h>
#include <cstdint>
#include <cstddef>

// Problem constants (fixed by setup_inputs)
constexpr int B_  = 16;
constexpr int T_  = 1024;
constexpr int C_  = 768;
constexpr int H_  = 12;
constexpr int HD_ = 64;
constexpr int BT_ = B_ * T_;      // 16384
constexpr int C3_ = 3 * C_;       // 2304
constexpr int FF_ = 4 * C_;       // 3072
constexpr int MCH_ = 8192;        // MoE row chunk

typedef __bf16 bf16x8 __attribute__((ext_vector_type(8)));
typedef float  floatx4 __attribute__((ext_vector_type(4)));
typedef unsigned short u16x8 __attribute__((ext_vector_type(8)));

__device__ inline float bf2f(unsigned short u) {
  union { unsigned int i; float f; } x; x.i = ((unsigned int)u) << 16; return x.f;
}
__device__ inline unsigned short f2bf(float f) {
  union { float f; unsigned int i; } x; x.f = f;
  unsigned int u = x.i;
  u += 0x7fffu + ((u >> 16) & 1u);   // round-to-nearest-even
  return (unsigned short)(u >> 16);
}

// async global->LDS, 16B per lane, LDS dest = wave-uniform base + lane*16
#define GLOAD_LDS16(gp, lp)                                              \
  __builtin_amdgcn_global_load_lds(                                      \
      (__attribute__((address_space(1))) void*)(gp),                     \
      (__attribute__((address_space(3))) void*)(lp), 16, 0, 0)

// ---------------------------------------------------------------------------
// LayerNorm: one block (256 threads) per row of 768. f32 in, bf16 out.
// ---------------------------------------------------------------------------
__launch_bounds__(256)
__global__ void ln_kernel(const float* __restrict__ x, const float* __restrict__ w,
                          const float* __restrict__ b, unsigned short* __restrict__ out) {
  int row = blockIdx.x;
  int tid = threadIdx.x;
  const float* xr = x + (size_t)row * C_;
  float v0 = xr[tid], v1 = xr[tid + 256], v2 = xr[tid + 512];
  float s  = v0 + v1 + v2;
  float ss = v0 * v0 + v1 * v1 + v2 * v2;
#pragma unroll
  for (int off = 32; off > 0; off >>= 1) {
    s  += __shfl_down(s, off, 64);
    ss += __shfl_down(ss, off, 64);
  }
  __shared__ float red[8];
  int wid = tid >> 6;
  if ((tid & 63) == 0) { red[wid] = s; red[4 + wid] = ss; }
  __syncthreads();
  float st  = red[0] + red[1] + red[2] + red[3];
  float sst = red[4] + red[5] + red[6] + red[7];
  float mean = st * (1.0f / C_);
  float var  = sst * (1.0f / C_) - mean * mean;
  float rstd = rsqrtf(var + 1e-5f);
  unsigned short* orow = out + (size_t)row * C_;
  orow[tid]       = f2bf((v0 - mean) * rstd * w[tid]       + b[tid]);
  orow[tid + 256] = f2bf((v1 - mean) * rstd * w[tid + 256] + b[tid + 256]);
  orow[tid + 512] = f2bf((v2 - mean) * rstd * w[tid + 512] + b[tid + 512]);
}

// ---------------------------------------------------------------------------
// Transpose+convert: in f32 [K,N] row-major -> out bf16 [N,K] row-major.
// ---------------------------------------------------------------------------
__launch_bounds__(256)
__global__ void convT(const float* __restrict__ in, unsigned short* __restrict__ out,
                      int K, int N) {
  __shared__ float t[32][33];
  int n0 = blockIdx.x * 32, k0 = blockIdx.y * 32;
  int tx = threadIdx.x & 31, ty = threadIdx.x >> 5;  // 8 rows per pass
#pragma unroll
  for (int r = 0; r < 32; r += 8)
    t[r + ty][tx] = in[(size_t)(k0 + r + ty) * N + n0 + tx];
  __syncthreads();
#pragma unroll
  for (int r = 0; r < 32; r += 8)
    out[(size_t)(n0 + r + ty) * K + k0 + tx] = f2bf(t[tx][r + ty]);
}

// ---------------------------------------------------------------------------
// bf16 MFMA GEMM: C = post(A @ Bt^T).  A[M,K] bf16, Bt[N,K] bf16 (pre-transposed).
// 128x128 tile / 256 threads (4 waves, each 64x64 via 4x4 of 16x16x32 MFMA).
// ---------------------------------------------------------------------------
template <int ACT, bool BIAS, bool RES, bool COMBINE, bool OUTBF16>
__launch_bounds__(256)
__global__ void gemm_bf16(const unsigned short* __restrict__ A,
                          const unsigned short* __restrict__ Bt,
                          const float* __restrict__ bias,
                          const float* __restrict__ Rres,
                          const float* __restrict__ gates2, int eidx,
                          void* __restrict__ Cout,
                          int M, int N, int K) {
  __shared__ __attribute__((aligned(16))) unsigned short Als[8192];
  __shared__ __attribute__((aligned(16))) unsigned short Bls[8192];
  const int tid  = threadIdx.x;
  const int wave = tid >> 6, lane = tid & 63;
  const int wr = wave >> 1, wc = wave & 1;
  const int m0 = blockIdx.y * 128, n0 = blockIdx.x * 128;

  const int srow = wave * 32 + (lane >> 3);
  const int skg  = (lane & 7) ^ ((lane >> 3) & 7);   // swizzled k-granule
  const unsigned short* Ap = A  + (size_t)(m0 + srow) * K + skg * 8;
  const unsigned short* Bp = Bt + (size_t)(n0 + srow) * K + skg * 8;
  unsigned short* AlsW = Als + wave * 2048;
  unsigned short* BlsW = Bls + wave * 2048;

  floatx4 acc[4][4];
#pragma unroll
  for (int i = 0; i < 4; ++i)
#pragma unroll
    for (int j = 0; j < 4; ++j) acc[i][j] = floatx4{0.f, 0.f, 0.f, 0.f};

  const int q  = lane >> 4;
  const int ml = lane & 15;
  const int rsw = ml & 7;

  for (int k0 = 0; k0 < K; k0 += 64) {
    __syncthreads();
#pragma unroll
    for (int i = 0; i < 4; ++i) {
      GLOAD_LDS16(Ap + (size_t)(i * 8) * K + k0, AlsW + i * 512);
      GLOAD_LDS16(Bp + (size_t)(i * 8) * K + k0, BlsW + i * 512);
    }
    __syncthreads();
#pragma unroll
    for (int ks = 0; ks < 2; ++ks) {
      const int p = (ks * 4 + q) ^ rsw;
      bf16x8 af[4], bfg[4];
#pragma unroll
      for (int i = 0; i < 4; ++i) {
        int ar = wr * 64 + i * 16 + ml;
        af[i]  = *(const bf16x8*)&Als[(ar * 8 + p) * 8];
        int br = wc * 64 + i * 16 + ml;
        bfg[i] = *(const bf16x8*)&Bls[(br * 8 + p) * 8];
      }
#pragma unroll
      for (int i = 0; i < 4; ++i)
#pragma unroll
        for (int j = 0; j < 4; ++j)
          acc[i][j] = __builtin_amdgcn_mfma_f32_16x16x32_bf16(af[i], bfg[j], acc[i][j], 0, 0, 0);
    }
  }

  const int rbase = q * 4;
#pragma unroll
  for (int i = 0; i < 4; ++i) {
    int row = m0 + wr * 64 + i * 16 + rbase;
#pragma unroll
    for (int j = 0; j < 4; ++j) {
      int col = n0 + wc * 64 + j * 16 + ml;
      float bcol = BIAS ? bias[col] : 0.f;
#pragma unroll
      for (int r = 0; r < 4; ++r) {
        float v = acc[i][j][r];
        if (BIAS) v += bcol;
        if (ACT == 1) v = (v >= 0.f) ? v : 0.01f * v;
        if (RES) v += Rres[(size_t)(row + r) * N + col];
        if (COMBINE) {
          float g = gates2[2 * (row + r) + eidx];
          float* op = (float*)Cout + (size_t)(row + r) * N + col;
          *op += g * v;
        } else if (OUTBF16) {
          ((unsigned short*)Cout)[(size_t)(row + r) * N + col] = f2bf(v);
        } else {
          ((float*)Cout)[(size_t)(row + r) * N + col] = v;
        }
      }
    }
  }
}

// ---------------------------------------------------------------------------
// MFMA flash attention. qkv: [B*T, 3C] bf16 (q|k|v, col = h*64+d). y: bf16.
// ---------------------------------------------------------------------------
__launch_bounds__(256)
__global__ void attn_kernel(const unsigned short* __restrict__ qkv,
                            unsigned short* __restrict__ y) {
  __shared__ __attribute__((aligned(16))) unsigned short Qls[64 * 64];
  __shared__ __attribute__((aligned(16))) unsigned short Kls[64 * 64];
  __shared__ __attribute__((aligned(16))) unsigned short Vt[64 * 72];
  __shared__ __attribute__((aligned(16))) unsigned short Pls[4 * 16 * 72];

  const int tid  = threadIdx.x;
  const int wave = tid >> 6, lane = tid & 63;
  const int quad = lane >> 4, n = lane & 15;
  const int q0 = blockIdx.x * 64;
  const int bh = blockIdx.y;
  const int b = bh / H_, h = bh % H_;
  const size_t base = (size_t)b * T_ * C3_ + (size_t)h * HD_;

  {
    const int r8 = lane >> 3;
    const int g  = (lane & 7) ^ r8;
#pragma unroll
    for (int i = 0; i < 2; ++i) {
      int row = wave * 16 + i * 8 + r8;
      GLOAD_LDS16(qkv + base + (size_t)(q0 + row) * C3_ + g * 8,
                  Qls + wave * 1024 + i * 512);
    }
  }

  floatx4 O[4];
#pragma unroll
  for (int ct = 0; ct < 4; ++ct) O[ct] = floatx4{0.f, 0.f, 0.f, 0.f};
  float mrow[4] = {-1e30f, -1e30f, -1e30f, -1e30f};
  float lrow[4] = {0.f, 0.f, 0.f, 0.f};

  const int nkt = blockIdx.x + 1;
  unsigned short* Pw = Pls + wave * (16 * 72);

  for (int kt = 0; kt < nkt; ++kt) {
    const int k0 = kt << 6;
    __syncthreads();
    {
      const int r8 = lane >> 3;
      const int g  = (lane & 7) ^ r8;
#pragma unroll
      for (int i = 0; i < 2; ++i) {
        int key = wave * 16 + i * 8 + r8;
        GLOAD_LDS16(qkv + base + (size_t)(k0 + key) * C3_ + C_ + g * 8,
                    Kls + wave * 1024 + i * 512);
      }
    }
    {
      int key = tid & 63;
      int dbase = (tid >> 6) * 8;
#pragma unroll
      for (int it = 0; it < 2; ++it) {
        int d0 = dbase + it * 32;
        u16x8 vv = *(const u16x8*)(qkv + base + (size_t)(k0 + key) * C3_ + 2 * C_ + d0);
#pragma unroll
        for (int j = 0; j < 8; ++j) Vt[(d0 + j) * 72 + key] = vv[j];
      }
    }
    __syncthreads();

    floatx4 sacc[4];
#pragma unroll
    for (int ct = 0; ct < 4; ++ct) sacc[ct] = floatx4{0.f, 0.f, 0.f, 0.f};
#pragma unroll
    for (int ks = 0; ks < 2; ++ks) {
      const int ga = (ks * 4 + quad) ^ (n & 7);
      bf16x8 aq = *(const bf16x8*)&Qls[((wave * 16 + n) * 8 + ga) * 8];
#pragma unroll
      for (int ct = 0; ct < 4; ++ct) {
        bf16x8 kb = *(const bf16x8*)&Kls[((ct * 16 + n) * 8 + ga) * 8];
        sacc[ct] = __builtin_amdgcn_mfma_f32_16x16x32_bf16(aq, kb, sacc[ct], 0, 0, 0);
      }
    }

    float p[4][4];
#pragma unroll
    for (int ct = 0; ct < 4; ++ct)
#pragma unroll
      for (int r = 0; r < 4; ++r) p[ct][r] = sacc[ct][r] * 0.125f;
    if (kt == nkt - 1) {
      const int kgb = k0 + n, qgb = q0 + wave * 16 + quad * 4;
#pragma unroll
      for (int ct = 0; ct < 4; ++ct)
#pragma unroll
        for (int r = 0; r < 4; ++r)
          if (kgb + ct * 16 > qgb + r) p[ct][r] = -1e30f;
    }
#pragma unroll
    for (int r = 0; r < 4; ++r) {
      float tm = fmaxf(fmaxf(p[0][r], p[1][r]), fmaxf(p[2][r], p[3][r]));
      tm = fmaxf(tm, __shfl_xor(tm, 1, 64));
      tm = fmaxf(tm, __shfl_xor(tm, 2, 64));
      tm = fmaxf(tm, __shfl_xor(tm, 4, 64));
      tm = fmaxf(tm, __shfl_xor(tm, 8, 64));
      float mn = fmaxf(mrow[r], tm);
      float alpha = __expf(mrow[r] - mn);
      mrow[r] = mn;
      float ps = 0.f;
#pragma unroll
      for (int ct = 0; ct < 4; ++ct) {
        float pe = __expf(p[ct][r] - mn);
        p[ct][r] = pe;
        ps += pe;
      }
      ps += __shfl_xor(ps, 1, 64);
      ps += __shfl_xor(ps, 2, 64);
      ps += __shfl_xor(ps, 4, 64);
      ps += __shfl_xor(ps, 8, 64);
      lrow[r] = lrow[r] * alpha + ps;
      O[0][r] *= alpha; O[1][r] *= alpha; O[2][r] *= alpha; O[3][r] *= alpha;
    }

#pragma unroll
    for (int ct = 0; ct < 4; ++ct)
#pragma unroll
      for (int r = 0; r < 4; ++r)
        Pw[(quad * 4 + r) * 72 + ct * 16 + n] = f2bf(p[ct][r]);

#pragma unroll
    for (int ks = 0; ks < 2; ++ks) {
      bf16x8 pa = *(const bf16x8*)&Pw[n * 72 + (ks * 4 + quad) * 8];
#pragma unroll
      for (int ct = 0; ct < 4; ++ct) {
        bf16x8 vb = *(const bf16x8*)&Vt[(ct * 16 + n) * 72 + (ks * 4 + quad) * 8];
        O[ct] = __builtin_amdgcn_mfma_f32_16x16x32_bf16(pa, vb, O[ct], 0, 0, 0);
      }
    }
  }

#pragma unroll
  for (int r = 0; r < 4; ++r) {
    float inv = 1.0f / lrow[r];
    int row = q0 + wave * 16 + quad * 4 + r;
    unsigned short* dst = y + ((size_t)b * T_ + row) * C_ + h * HD_;
#pragma unroll
    for (int ct = 0; ct < 4; ++ct)
      dst[ct * 16 + n] = f2bf(O[ct][r] * inv);
  }
}

// ---------------------------------------------------------------------------
// Gating: one wave per token; h2 is bf16. Writes gates only (NO atomics).
// ---------------------------------------------------------------------------
__launch_bounds__(256)
__global__ void gate_kernel(const unsigned short* __restrict__ h2,
                            const float* __restrict__ wg,
                            float* __restrict__ gates) {
  int wave = threadIdx.x >> 6, lane = threadIdx.x & 63;
  int t = blockIdx.x * 4 + wave;
  const unsigned short* hr = h2 + (size_t)t * C_;
  float a0 = 0.0f, a1 = 0.0f;
#pragma unroll
  for (int i = 0; i < 12; ++i) {
    int d = lane + 64 * i;
    float hv = bf2f(hr[d]);
    a0 += hv * wg[2 * d];
    a1 += hv * wg[2 * d + 1];
  }
#pragma unroll
  for (int off = 32; off > 0; off >>= 1) {
    a0 += __shfl_down(a0, off, 64);
    a1 += __shfl_down(a1, off, 64);
  }
  if (lane == 0) {
    float m  = fmaxf(a0, a1);
    float e0 = __expf(a0 - m), e1 = __expf(a1 - m);
    float invs = 1.0f / (e0 + e1);
    float p0 = e0 * invs, p1 = e1 * invs;
    const float gnorm = 1.0f / (1.0f + 1e-9f);
    gates[2 * t]     = p0 * gnorm;
    gates[2 * t + 1] = p1 * gnorm;
  }
}

// ---------------------------------------------------------------------------
// MoE stats + aux loss: single block, 1024 threads = 16 waves; wave w = batch w.
// Reads gates (131 KB, L2-resident), zero global atomics.
// aux = mean_{b,e}(density * proxy) * E^2
// ---------------------------------------------------------------------------
__launch_bounds__(1024)
__global__ void moe_stats_kernel(const float* __restrict__ gates,
                                 float* __restrict__ out_aux) {
  int wave = threadIdx.x >> 6, lane = threadIdx.x & 63;
  float c0 = 0.f, sp0 = 0.f, sp1 = 0.f;
#pragma unroll
  for (int j = 0; j < 16; ++j) {
    int t = wave * T_ + lane + 64 * j;
    float p0 = gates[2 * t], p1 = gates[2 * t + 1];
    c0  += (p1 > p0) ? 0.f : 1.f;   // argmax==0 count (ties -> expert 0)
    sp0 += p0;
    sp1 += p1;
  }
#pragma unroll
  for (int off = 32; off > 0; off >>= 1) {
    c0  += __shfl_down(c0, off, 64);
    sp0 += __shfl_down(sp0, off, 64);
    sp1 += __shfl_down(sp1, off, 64);
  }
  __shared__ float red[16][3];
  if (lane == 0) { red[wave][0] = c0; red[wave][1] = sp0; red[wave][2] = sp1; }
  __syncthreads();
  if (threadIdx.x == 0) {
    float s = 0.f;
    for (int b = 0; b < B_; ++b) {
      float cc0 = red[b][0];
      float d0 = cc0 * (1.f / T_), d1 = (T_ - cc0) * (1.f / T_);
      float px0 = red[b][1] * (1.f / T_), px1 = red[b][2] * (1.f / T_);
      s += d0 * px0 + d1 * px1;
    }
    out_aux[0] = s * (4.f / 32.f);   // * E*E / (B*E)
  }
}

// ---------------------------------------------------------------------------
extern "C" void kernel_launch(void* const* d_in, const int* in_sizes, int n_in,
                              void* d_out, int out_size, void* d_ws, size_t ws_size,
                              hipStream_t stream) {
  const float* x     = (const float*)d_in[0];
  const float* ln1_w = (const float*)d_in[1];
  const float* ln1_b = (const float*)d_in[2];
  const float* wqkv  = (const float*)d_in[3];
  const float* bqkv  = (const float*)d_in[4];
  const float* wproj = (const float*)d_in[5];
  const float* bproj = (const float*)d_in[6];
  const float* ln2_w = (const float*)d_in[7];
  const float* ln2_b = (const float*)d_in[8];
  const float* wg    = (const float*)d_in[9];
  const float* w1    = (const float*)d_in[10];
  const float* w2    = (const float*)d_in[11];
  const float* w3    = (const float*)d_in[12];
  float* out = (float*)d_out;

  // workspace layout (ushort units)
  unsigned short* wsu   = (unsigned short*)d_ws;
  unsigned short* wqkvT = wsu;                                   // 2304*768
  unsigned short* wprojT= wqkvT + (size_t)C3_ * C_;              // 768*768
  unsigned short* w1T   = wprojT + (size_t)C_ * C_;              // 2*3072*768
  unsigned short* w2T   = w1T + (size_t)2 * FF_ * C_;            // 2*3072*3072
  unsigned short* w3T   = w2T + (size_t)2 * FF_ * FF_;           // 2*768*3072
  unsigned short* hb    = w3T + (size_t)2 * C_ * FF_;            // BT*C
  unsigned short* region= hb + (size_t)BT_ * C_;                 // BT*4C (union)
  unsigned short* qkvb  = region;                                // BT*3C
  unsigned short* yb    = region + (size_t)BT_ * C3_;            // BT*C
  unsigned short* hh1   = region;                                // MCH*FF
  unsigned short* hh2   = region + (size_t)MCH_ * FF_;           // MCH*FF
  float* gates = (float*)(region + (size_t)BT_ * 4 * C_);        // BT*2

  // ---- weight transpose+convert ----
  convT<<<dim3(C3_ / 32, C_ / 32), 256, 0, stream>>>(wqkv, wqkvT, C_, C3_);
  convT<<<dim3(C_ / 32, C_ / 32), 256, 0, stream>>>(wproj, wprojT, C_, C_);
  for (int e = 0; e < 2; ++e) {
    convT<<<dim3(FF_ / 32, C_ / 32), 256, 0, stream>>>(
        w1 + (size_t)e * C_ * FF_, w1T + (size_t)e * FF_ * C_, C_, FF_);
    convT<<<dim3(FF_ / 32, FF_ / 32), 256, 0, stream>>>(
        w2 + (size_t)e * FF_ * FF_, w2T + (size_t)e * FF_ * FF_, FF_, FF_);
    convT<<<dim3(C_ / 32, FF_ / 32), 256, 0, stream>>>(
        w3 + (size_t)e * FF_ * C_, w3T + (size_t)e * C_ * FF_, FF_, C_);
  }

  // ---- attention path ----
  ln_kernel<<<BT_, 256, 0, stream>>>(x, ln1_w, ln1_b, hb);
  gemm_bf16<0, true, false, false, true><<<dim3(C3_ / 128, BT_ / 128), 256, 0, stream>>>(
      hb, wqkvT, bqkv, nullptr, nullptr, 0, qkvb, BT_, C3_, C_);
  attn_kernel<<<dim3(T_ / 64, B_ * H_), 256, 0, stream>>>(qkvb, yb);
  gemm_bf16<0, true, true, false, false><<<dim3(C_ / 128, BT_ / 128), 256, 0, stream>>>(
      yb, wprojT, bproj, x, nullptr, 0, out, BT_, C_, C_);

  // ---- MoE path (dense: E=2 top-2 -> every token hits both experts) ----
  ln_kernel<<<BT_, 256, 0, stream>>>(out, ln2_w, ln2_b, hb);
  gate_kernel<<<BT_ / 4, 256, 0, stream>>>(hb, wg, gates);
  moe_stats_kernel<<<1, 1024, 0, stream>>>(gates, out + (size_t)BT_ * C_);

  for (int e = 0; e < 2; ++e) {
    for (int c = 0; c < BT_ / MCH_; ++c) {
      const unsigned short* a = hb + (size_t)c * MCH_ * C_;
      gemm_bf16<1, false, false, false, true><<<dim3(FF_ / 128, MCH_ / 128), 256, 0, stream>>>(
          a, w1T + (size_t)e * FF_ * C_, nullptr, nullptr, nullptr, 0, hh1, MCH_, FF_, C_);
      gemm_bf16<1, false, false, false, true><<<dim3(FF_ / 128, MCH_ / 128), 256, 0, stream>>>(
          hh1, w2T + (size_t)e * FF_ * FF_, nullptr, nullptr, nullptr, 0, hh2, MCH_, FF_, FF_);
      gemm_bf16<0, false, false, true, false><<<dim3(C_ / 128, MCH_ / 128), 256, 0, stream>>>(
          hh2, w3T + (size_t)e * C_ * FF_, nullptr, nullptr,
          gates + (size_t)2 * c * MCH_, e, out + (size_t)c * MCH_ * C_, MCH_, C_, FF_);
    }
  }
}